// Round 2
// baseline (313.252 us; speedup 1.0000x reference)
//
#include <hip/hip_runtime.h>

#define NB 8
#define NA 120000
#define NK 80
#define NM 32

#define ALPHA_F 0.25f
#define EPS_F 1e-4f

// ws layout:
//   bytes [0,128):    float acc[32]  (cls_sum[8], reg_sum[8], num_pos[8], pad)
//   bytes [128,160):  int   cnt_ign[8]
//   bytes [512, ...): int   ign_list[8][NA]   (per-b regions, stride NA ints)
#define ACC_CLS 0
#define ACC_REG 8
#define ACC_NP  16

#define BLK_A 256
#define BPB_A ((NA + BLK_A - 1) / BLK_A)   // 469 blocks per batch item

// focal main: per b, 2,400,000 float4 = 625 blocks * 256 threads * 15 iters
#define FB_BPB 625
#define FB_STRIDE (FB_BPB * 256)           // 160,000
#define FB_U 5
#define FB_O 3                              // 3 outer * 5 unrolled = 15

#define IG_BPB 64                           // blocks per b for ignore correction

__global__ void init_acc(float* __restrict__ acc, int* __restrict__ cnt) {
    if (threadIdx.x < 32) acc[threadIdx.x] = 0.0f;
    if (threadIdx.x < 8) cnt[threadIdx.x] = 0;
}

__device__ __forceinline__ float clampc(float x) {
    return fminf(fmaxf(x, EPS_F), 1.0f - EPS_F);
}
__device__ __forceinline__ float negl(float c) {
    // t == 0: (1-alpha) * c^2 * (-log(1-c))
    return (1.0f - ALPHA_F) * c * c * (-__logf(1.0f - c));
}
__device__ __forceinline__ float posl(float c) {
    // t == 1: alpha * (1-c)^2 * (-log(c))
    const float omc = 1.0f - c;
    return ALPHA_F * omc * omc * (-__logf(c));
}
__device__ __forceinline__ float negl4(float4 v) {
    return negl(clampc(v.x)) + negl(clampc(v.y)) + negl(clampc(v.z)) + negl(clampc(v.w));
}

__global__ __launch_bounds__(BLK_A) void assign_kernel(
    const float* __restrict__ anchors,      // [NA,4]
    const float* __restrict__ regressions,  // [NB,NA,4]
    const float* __restrict__ annotations,  // [NB,NM,5]
    const float* __restrict__ cls,          // [NB,NA,NK]
    float* __restrict__ acc,
    int* __restrict__ cnt_ign,
    int* __restrict__ ign_list)
{
    const int b = blockIdx.x / BPB_A;
    const int a = (blockIdx.x % BPB_A) * BLK_A + threadIdx.x;

    __shared__ float ann[NM * 5];
    if (threadIdx.x < NM * 5) ann[threadIdx.x] = annotations[b * NM * 5 + threadIdx.x];
    __syncthreads();

    float reg_local = 0.0f;
    float pos_local = 0.0f;
    float cls_local = 0.0f;   // positive-class correction: posl - negl at assigned class

    if (a < NA) {
        const float4 av = ((const float4*)anchors)[a];
        const float aw = av.z - av.x;
        const float ah = av.w - av.y;
        const float aarea = aw * ah;

        float best = -1e30f;
        int bm = 0;
        #pragma unroll
        for (int m = 0; m < NM; ++m) {
            const float bx1 = ann[m * 5 + 0];
            const float by1 = ann[m * 5 + 1];
            const float bx2 = ann[m * 5 + 2];
            const float by2 = ann[m * 5 + 3];
            const float lbl = ann[m * 5 + 4];
            float iw = fmaxf(fminf(av.z, bx2) - fmaxf(av.x, bx1), 0.0f);
            float ih = fmaxf(fminf(av.w, by2) - fmaxf(av.y, by1), 0.0f);
            const float inter = iw * ih;
            const float ua = fmaxf(aarea + (bx2 - bx1) * (by2 - by1) - inter, 1e-8f);
            float iou = inter / ua;
            if (lbl == -1.0f) iou = -1.0f;             // padding mask
            if (iou > best) { best = iou; bm = m; }     // strict > == first-occurrence argmax
        }

        if (best >= 0.5f) {
            const int st = (int)ann[bm * 5 + 4];
            // regression loss for positive anchor
            const float bx1 = ann[bm * 5 + 0];
            const float by1 = ann[bm * 5 + 1];
            const float bx2 = ann[bm * 5 + 2];
            const float by2 = ann[bm * 5 + 3];
            const float gw0 = bx2 - bx1;
            const float gh0 = by2 - by1;
            const float gcx = bx1 + 0.5f * gw0;
            const float gcy = by1 + 0.5f * gh0;
            const float gw = fmaxf(gw0, 1.0f);
            const float gh = fmaxf(gh0, 1.0f);
            const float acx = av.x + 0.5f * aw;
            const float acy = av.y + 0.5f * ah;
            float rt0 = ((gcx - acx) / aw) / 0.1f;
            float rt1 = ((gcy - acy) / ah) / 0.1f;
            float rt2 = logf(gw / aw) / 0.2f;
            float rt3 = logf(gh / ah) / 0.2f;
            const float4 rg = ((const float4*)regressions)[b * NA + a];
            float s = 0.0f;
            float d;
            d = fabsf(rt0 - rg.x); s += (d <= 1.0f / 9.0f) ? 4.5f * d * d : d - 0.5f / 9.0f;
            d = fabsf(rt1 - rg.y); s += (d <= 1.0f / 9.0f) ? 4.5f * d * d : d - 0.5f / 9.0f;
            d = fabsf(rt2 - rg.z); s += (d <= 1.0f / 9.0f) ? 4.5f * d * d : d - 0.5f / 9.0f;
            d = fabsf(rt3 - rg.w); s += (d <= 1.0f / 9.0f) ? 4.5f * d * d : d - 0.5f / 9.0f;
            reg_local = s;
            pos_local = 1.0f;
            // single-element classification correction for the assigned class
            const float c = clampc(cls[((size_t)b * NA + a) * NK + st]);
            cls_local = posl(c) - negl(c);
        } else if (best >= 0.4f) {
            // ignore anchor: whole row must be excluded -> compact into list
            const int idx = atomicAdd(&cnt_ign[b], 1);
            ign_list[b * NA + idx] = a;
        }
    }

    // block reduction of (reg_local, pos_local, cls_local)
    #pragma unroll
    for (int o = 32; o > 0; o >>= 1) {
        reg_local += __shfl_down(reg_local, o, 64);
        pos_local += __shfl_down(pos_local, o, 64);
        cls_local += __shfl_down(cls_local, o, 64);
    }
    __shared__ float wr[BLK_A / 64], wp[BLK_A / 64], wc[BLK_A / 64];
    const int lane = threadIdx.x & 63;
    const int wid = threadIdx.x >> 6;
    if (lane == 0) { wr[wid] = reg_local; wp[wid] = pos_local; wc[wid] = cls_local; }
    __syncthreads();
    if (threadIdx.x == 0) {
        float rsum = 0.0f, psum = 0.0f, csum = 0.0f;
        #pragma unroll
        for (int i = 0; i < BLK_A / 64; ++i) { rsum += wr[i]; psum += wp[i]; csum += wc[i]; }
        atomicAdd(&acc[ACC_REG + b], rsum);
        atomicAdd(&acc[ACC_NP + b], psum);
        atomicAdd(&acc[ACC_CLS + b], csum);
    }
}

// Pure-stream focal loss: sum negl over EVERY element (corrections elsewhere).
__global__ __launch_bounds__(256) void focal_main(
    const float* __restrict__ cls,          // [NB,NA,NK]
    float* __restrict__ acc)
{
    const int b = blockIdx.x / FB_BPB;
    const int blk = blockIdx.x % FB_BPB;
    const float4* __restrict__ p = (const float4*)(cls + (size_t)b * NA * NK);
    const int t = blk * 256 + threadIdx.x;

    float sum = 0.0f;
    #pragma unroll
    for (int o = 0; o < FB_O; ++o) {
        float4 v[FB_U];
        #pragma unroll
        for (int u = 0; u < FB_U; ++u)
            v[u] = p[t + (o * FB_U + u) * FB_STRIDE];
        #pragma unroll
        for (int u = 0; u < FB_U; ++u)
            sum += negl4(v[u]);
    }

    #pragma unroll
    for (int o = 32; o > 0; o >>= 1) sum += __shfl_down(sum, o, 64);
    __shared__ float ws[256 / 64];
    const int lane = threadIdx.x & 63;
    const int wid = threadIdx.x >> 6;
    if (lane == 0) ws[wid] = sum;
    __syncthreads();
    if (threadIdx.x == 0) {
        float s = 0.0f;
        #pragma unroll
        for (int i = 0; i < 4; ++i) s += ws[i];
        atomicAdd(&acc[ACC_CLS + b], s);
    }
}

// Subtract the full-row negl sums of ignore anchors.
__global__ __launch_bounds__(256) void ignore_corr(
    const float* __restrict__ cls,
    const int* __restrict__ cnt_ign,
    const int* __restrict__ ign_list,
    float* __restrict__ acc)
{
    const int b = blockIdx.x / IG_BPB;
    const int blk = blockIdx.x % IG_BPB;
    const int n = cnt_ign[b];
    const int total = n * 20;               // 20 float4 per anchor row
    const int* lst = ign_list + b * NA;
    const float* base = cls + (size_t)b * NA * NK;

    float sum = 0.0f;
    for (int w = blk * 256 + threadIdx.x; w < total; w += IG_BPB * 256) {
        const int e = w / 20;
        const int f = w - e * 20;
        const int a = lst[e];
        const float4 v = ((const float4*)(base + (size_t)a * NK))[f];
        sum -= negl4(v);
    }

    #pragma unroll
    for (int o = 32; o > 0; o >>= 1) sum += __shfl_down(sum, o, 64);
    __shared__ float ws[256 / 64];
    const int lane = threadIdx.x & 63;
    const int wid = threadIdx.x >> 6;
    if (lane == 0) ws[wid] = sum;
    __syncthreads();
    if (threadIdx.x == 0) {
        float s = 0.0f;
        #pragma unroll
        for (int i = 0; i < 4; ++i) s += ws[i];
        atomicAdd(&acc[ACC_CLS + b], s);
    }
}

__global__ void finalize_kernel(const float* __restrict__ acc, float* __restrict__ out) {
    if (threadIdx.x == 0) {
        float cs = 0.0f, rs = 0.0f;
        #pragma unroll
        for (int b = 0; b < NB; ++b) {
            const float np = acc[ACC_NP + b];
            cs += acc[ACC_CLS + b] / fmaxf(np, 1.0f);
            rs += (np > 0.0f) ? acc[ACC_REG + b] / fmaxf(np * 4.0f, 1.0f) : 0.0f;
        }
        out[0] = cs / (float)NB;
        out[1] = rs / (float)NB;
    }
}

extern "C" void kernel_launch(void* const* d_in, const int* in_sizes, int n_in,
                              void* d_out, int out_size, void* d_ws, size_t ws_size,
                              hipStream_t stream) {
    const float* cls = (const float*)d_in[0];   // [NB,NA,NK]
    const float* reg = (const float*)d_in[1];   // [NB,NA,4]
    const float* anc = (const float*)d_in[2];   // [1,NA,4]
    const float* ann = (const float*)d_in[3];   // [NB,NM,5]

    float* acc = (float*)d_ws;
    int* cnt_ign = (int*)((char*)d_ws + 128);
    int* ign_list = (int*)((char*)d_ws + 512);
    float* out = (float*)d_out;

    init_acc<<<1, 64, 0, stream>>>(acc, cnt_ign);
    focal_main<<<NB * FB_BPB, 256, 0, stream>>>(cls, acc);
    assign_kernel<<<NB * BPB_A, BLK_A, 0, stream>>>(anc, reg, ann, cls, acc, cnt_ign, ign_list);
    ignore_corr<<<NB * IG_BPB, 256, 0, stream>>>(cls, cnt_ign, ign_list, acc);
    finalize_kernel<<<1, 64, 0, stream>>>(acc, out);
}

// Round 3
// 218.129 us; speedup vs baseline: 1.4361x; 1.4361x over previous
//
#include <hip/hip_runtime.h>

#define NB 8
#define NA 120000
#define NK 80
#define NM 32

#define ALPHA_F 0.25f
#define EPS_F 1e-4f

// ws layout:
//   bytes [0,128):    float acc[32]  (cls_sum[8], reg_sum[8], num_pos[8], pad)
//   bytes [128,160):  int   cnt_ign[8]
//   bytes [512, ...): int   ign_list[8][NA]   (per-b regions, stride NA ints)
#define ACC_CLS 0
#define ACC_REG 8
#define ACC_NP  16

#define BLK_A 256
#define BPB_A ((NA + BLK_A - 1) / BLK_A)   // 469 blocks per batch item

// focal main: per b, 2,400,000 float4 = 625 blocks * 256 threads * 15 iters
#define FB_BPB 625
#define FB_STRIDE (FB_BPB * 256)           // 160,000
#define FB_U 5
#define FB_O 3                              // 3 outer * 5 unrolled = 15

#define IG_BPB 64                           // blocks per b for ignore correction

__global__ void init_acc(float* __restrict__ acc, int* __restrict__ cnt) {
    if (threadIdx.x < 32) acc[threadIdx.x] = 0.0f;
    if (threadIdx.x < 8) cnt[threadIdx.x] = 0;
}

__device__ __forceinline__ float clampc(float x) {
    return fminf(fmaxf(x, EPS_F), 1.0f - EPS_F);
}
__device__ __forceinline__ float negl(float c) {
    // t == 0: (1-alpha) * c^2 * (-log(1-c))
    return (1.0f - ALPHA_F) * c * c * (-__logf(1.0f - c));
}
__device__ __forceinline__ float posl(float c) {
    // t == 1: alpha * (1-c)^2 * (-log(c))
    const float omc = 1.0f - c;
    return ALPHA_F * omc * omc * (-__logf(c));
}
__device__ __forceinline__ float negl4(float4 v) {
    return negl(clampc(v.x)) + negl(clampc(v.y)) + negl(clampc(v.z)) + negl(clampc(v.w));
}

__global__ __launch_bounds__(BLK_A) void assign_kernel(
    const float* __restrict__ anchors,      // [NA,4]
    const float* __restrict__ regressions,  // [NB,NA,4]
    const float* __restrict__ annotations,  // [NB,NM,5]
    const float* __restrict__ cls,          // [NB,NA,NK]
    float* __restrict__ acc,
    int* __restrict__ cnt_ign,
    int* __restrict__ ign_list)
{
    const int b = blockIdx.x / BPB_A;
    const int a = (blockIdx.x % BPB_A) * BLK_A + threadIdx.x;

    __shared__ float ann[NM * 5];
    __shared__ float barea[NM];
    __shared__ int s_cnt, s_base;
    if (threadIdx.x == 0) s_cnt = 0;
    if (threadIdx.x < NM * 5) ann[threadIdx.x] = annotations[b * NM * 5 + threadIdx.x];
    __syncthreads();
    if (threadIdx.x < NM) {
        const float* r = &ann[threadIdx.x * 5];
        barea[threadIdx.x] = (r[2] - r[0]) * (r[3] - r[1]);
    }
    __syncthreads();

    float reg_local = 0.0f;
    float pos_local = 0.0f;
    float cls_local = 0.0f;   // positive-class correction: posl - negl at assigned class
    int my_idx = -1;          // slot in the block-local ignore list

    if (a < NA) {
        const float4 av = ((const float4*)anchors)[a];
        const float aw = av.z - av.x;
        const float ah = av.w - av.y;
        const float aarea = aw * ah;

        // division-free running argmax: track (best_inter, best_ua), all ua > 0.
        float bi = -1.0f, bu = 1.0f;   // represents iou = -1 (masked)
        int bm = 0;
        #pragma unroll
        for (int m = 0; m < NM; ++m) {
            const float bx1 = ann[m * 5 + 0];
            const float by1 = ann[m * 5 + 1];
            const float bx2 = ann[m * 5 + 2];
            const float by2 = ann[m * 5 + 3];
            const float lbl = ann[m * 5 + 4];
            const float iw = fmaxf(fminf(av.z, bx2) - fmaxf(av.x, bx1), 0.0f);
            const float ih = fmaxf(fminf(av.w, by2) - fmaxf(av.y, by1), 0.0f);
            float inter = iw * ih;
            float ua = fmaxf(aarea + barea[m] - inter, 1e-8f);
            if (lbl == -1.0f) { inter = -1.0f; ua = 1.0f; }   // padding mask -> iou = -1
            // iou_m > best  <=>  inter * bu > bi * ua   (strict > keeps first occurrence)
            if (m == 0 || inter * bu > bi * ua) { bi = inter; bu = ua; bm = m; }
        }

        if (bi >= 0.5f * bu) {
            const int st = (int)ann[bm * 5 + 4];
            // regression loss for positive anchor
            const float bx1 = ann[bm * 5 + 0];
            const float by1 = ann[bm * 5 + 1];
            const float bx2 = ann[bm * 5 + 2];
            const float by2 = ann[bm * 5 + 3];
            const float gw0 = bx2 - bx1;
            const float gh0 = by2 - by1;
            const float gcx = bx1 + 0.5f * gw0;
            const float gcy = by1 + 0.5f * gh0;
            const float gw = fmaxf(gw0, 1.0f);
            const float gh = fmaxf(gh0, 1.0f);
            const float acx = av.x + 0.5f * aw;
            const float acy = av.y + 0.5f * ah;
            float rt0 = ((gcx - acx) / aw) / 0.1f;
            float rt1 = ((gcy - acy) / ah) / 0.1f;
            float rt2 = logf(gw / aw) / 0.2f;
            float rt3 = logf(gh / ah) / 0.2f;
            const float4 rg = ((const float4*)regressions)[b * NA + a];
            float s = 0.0f;
            float d;
            d = fabsf(rt0 - rg.x); s += (d <= 1.0f / 9.0f) ? 4.5f * d * d : d - 0.5f / 9.0f;
            d = fabsf(rt1 - rg.y); s += (d <= 1.0f / 9.0f) ? 4.5f * d * d : d - 0.5f / 9.0f;
            d = fabsf(rt2 - rg.z); s += (d <= 1.0f / 9.0f) ? 4.5f * d * d : d - 0.5f / 9.0f;
            d = fabsf(rt3 - rg.w); s += (d <= 1.0f / 9.0f) ? 4.5f * d * d : d - 0.5f / 9.0f;
            reg_local = s;
            pos_local = 1.0f;
            // single-element classification correction for the assigned class
            const float c = clampc(cls[((size_t)b * NA + a) * NK + st]);
            cls_local = posl(c) - negl(c);
        } else if (bi >= 0.4f * bu) {
            // ignore anchor: block-local compaction (LDS atomic), one global atomic/block
            my_idx = atomicAdd(&s_cnt, 1);
        }
        // else: negative, nothing to do (focal_main already counted the row)
    }

    __syncthreads();
    if (threadIdx.x == 0 && s_cnt > 0) s_base = atomicAdd(&cnt_ign[b], s_cnt);
    __syncthreads();
    if (my_idx >= 0) ign_list[b * NA + s_base + my_idx] = a;

    // block reduction of (reg_local, pos_local, cls_local)
    #pragma unroll
    for (int o = 32; o > 0; o >>= 1) {
        reg_local += __shfl_down(reg_local, o, 64);
        pos_local += __shfl_down(pos_local, o, 64);
        cls_local += __shfl_down(cls_local, o, 64);
    }
    __shared__ float wr[BLK_A / 64], wp[BLK_A / 64], wc[BLK_A / 64];
    const int lane = threadIdx.x & 63;
    const int wid = threadIdx.x >> 6;
    if (lane == 0) { wr[wid] = reg_local; wp[wid] = pos_local; wc[wid] = cls_local; }
    __syncthreads();
    if (threadIdx.x == 0) {
        float rsum = 0.0f, psum = 0.0f, csum = 0.0f;
        #pragma unroll
        for (int i = 0; i < BLK_A / 64; ++i) { rsum += wr[i]; psum += wp[i]; csum += wc[i]; }
        atomicAdd(&acc[ACC_REG + b], rsum);
        atomicAdd(&acc[ACC_NP + b], psum);
        atomicAdd(&acc[ACC_CLS + b], csum);
    }
}

// Pure-stream focal loss: sum negl over EVERY element (corrections elsewhere).
__global__ __launch_bounds__(256) void focal_main(
    const float* __restrict__ cls,          // [NB,NA,NK]
    float* __restrict__ acc)
{
    const int b = blockIdx.x / FB_BPB;
    const int blk = blockIdx.x % FB_BPB;
    const float4* __restrict__ p = (const float4*)(cls + (size_t)b * NA * NK);
    const int t = blk * 256 + threadIdx.x;

    float sum = 0.0f;
    #pragma unroll
    for (int o = 0; o < FB_O; ++o) {
        float4 v[FB_U];
        #pragma unroll
        for (int u = 0; u < FB_U; ++u)
            v[u] = p[t + (o * FB_U + u) * FB_STRIDE];
        #pragma unroll
        for (int u = 0; u < FB_U; ++u)
            sum += negl4(v[u]);
    }

    #pragma unroll
    for (int o = 32; o > 0; o >>= 1) sum += __shfl_down(sum, o, 64);
    __shared__ float ws[256 / 64];
    const int lane = threadIdx.x & 63;
    const int wid = threadIdx.x >> 6;
    if (lane == 0) ws[wid] = sum;
    __syncthreads();
    if (threadIdx.x == 0) {
        float s = 0.0f;
        #pragma unroll
        for (int i = 0; i < 4; ++i) s += ws[i];
        atomicAdd(&acc[ACC_CLS + b], s);
    }
}

// Subtract the full-row negl sums of ignore anchors.
__global__ __launch_bounds__(256) void ignore_corr(
    const float* __restrict__ cls,
    const int* __restrict__ cnt_ign,
    const int* __restrict__ ign_list,
    float* __restrict__ acc)
{
    const int b = blockIdx.x / IG_BPB;
    const int blk = blockIdx.x % IG_BPB;
    const int n = cnt_ign[b];
    const int total = n * 20;               // 20 float4 per anchor row
    const int* lst = ign_list + b * NA;
    const float* base = cls + (size_t)b * NA * NK;

    float sum = 0.0f;
    for (int w = blk * 256 + threadIdx.x; w < total; w += IG_BPB * 256) {
        const int e = w / 20;
        const int f = w - e * 20;
        const int a = lst[e];
        const float4 v = ((const float4*)(base + (size_t)a * NK))[f];
        sum -= negl4(v);
    }

    #pragma unroll
    for (int o = 32; o > 0; o >>= 1) sum += __shfl_down(sum, o, 64);
    __shared__ float ws[256 / 64];
    const int lane = threadIdx.x & 63;
    const int wid = threadIdx.x >> 6;
    if (lane == 0) ws[wid] = sum;
    __syncthreads();
    if (threadIdx.x == 0) {
        float s = 0.0f;
        #pragma unroll
        for (int i = 0; i < 4; ++i) s += ws[i];
        atomicAdd(&acc[ACC_CLS + b], s);
    }
}

__global__ void finalize_kernel(const float* __restrict__ acc, float* __restrict__ out) {
    if (threadIdx.x == 0) {
        float cs = 0.0f, rs = 0.0f;
        #pragma unroll
        for (int b = 0; b < NB; ++b) {
            const float np = acc[ACC_NP + b];
            cs += acc[ACC_CLS + b] / fmaxf(np, 1.0f);
            rs += (np > 0.0f) ? acc[ACC_REG + b] / fmaxf(np * 4.0f, 1.0f) : 0.0f;
        }
        out[0] = cs / (float)NB;
        out[1] = rs / (float)NB;
    }
}

extern "C" void kernel_launch(void* const* d_in, const int* in_sizes, int n_in,
                              void* d_out, int out_size, void* d_ws, size_t ws_size,
                              hipStream_t stream) {
    const float* cls = (const float*)d_in[0];   // [NB,NA,NK]
    const float* reg = (const float*)d_in[1];   // [NB,NA,4]
    const float* anc = (const float*)d_in[2];   // [1,NA,4]
    const float* ann = (const float*)d_in[3];   // [NB,NM,5]

    float* acc = (float*)d_ws;
    int* cnt_ign = (int*)((char*)d_ws + 128);
    int* ign_list = (int*)((char*)d_ws + 512);
    float* out = (float*)d_out;

    init_acc<<<1, 64, 0, stream>>>(acc, cnt_ign);
    focal_main<<<NB * FB_BPB, 256, 0, stream>>>(cls, acc);
    assign_kernel<<<NB * BPB_A, BLK_A, 0, stream>>>(anc, reg, ann, cls, acc, cnt_ign, ign_list);
    ignore_corr<<<NB * IG_BPB, 256, 0, stream>>>(cls, cnt_ign, ign_list, acc);
    finalize_kernel<<<1, 64, 0, stream>>>(acc, out);
}

// Round 4
// 122.232 us; speedup vs baseline: 2.5628x; 1.7845x over previous
//
#include <hip/hip_runtime.h>

#define NB 8
#define NA 120000
#define NK 80
#define NM 32

#define ALPHA_F 0.25f
#define EPS_F 1e-4f

#define BLK_A 256
#define BPB_A ((NA + BLK_A - 1) / BLK_A)   // 469 blocks per batch item

// focal main: per b, 2,400,000 float4 = 625 blocks * 256 threads * 15 iters
#define FB_BPB 625
#define FB_STRIDE (FB_BPB * 256)           // 160,000
#define FB_U 5
#define FB_O 3                              // 3 outer * 5 unrolled = 15

// ws layout (no atomics, no init needed -- every read slot is written each launch):
//   f_part: float[NB*FB_BPB]      at byte 0      (5000 floats)
//   a_part: float[NB*BPB_A*3]     at byte 32768  (cls,reg,pos per assign block)
#define A_PART_OFF 32768

__device__ __forceinline__ float clampc(float x) {
    return fminf(fmaxf(x, EPS_F), 1.0f - EPS_F);
}
__device__ __forceinline__ float negl(float c) {
    // t == 0: (1-alpha) * c^2 * (-log(1-c))
    return (1.0f - ALPHA_F) * c * c * (-__logf(1.0f - c));
}
__device__ __forceinline__ float posl(float c) {
    // t == 1: alpha * (1-c)^2 * (-log(c))
    const float omc = 1.0f - c;
    return ALPHA_F * omc * omc * (-__logf(c));
}
__device__ __forceinline__ float negl4(float4 v) {
    return negl(clampc(v.x)) + negl(clampc(v.y)) + negl(clampc(v.z)) + negl(clampc(v.w));
}

__global__ __launch_bounds__(BLK_A) void assign_kernel(
    const float* __restrict__ anchors,      // [NA,4]
    const float* __restrict__ regressions,  // [NB,NA,4]
    const float* __restrict__ annotations,  // [NB,NM,5]
    const float* __restrict__ cls,          // [NB,NA,NK]
    float* __restrict__ a_part)             // [NB*BPB_A, 3] plain stores
{
    const int b = blockIdx.x / BPB_A;
    const int a = (blockIdx.x % BPB_A) * BLK_A + threadIdx.x;

    __shared__ float ann[NM * 5];
    __shared__ float barea[NM];
    if (threadIdx.x < NM * 5) ann[threadIdx.x] = annotations[b * NM * 5 + threadIdx.x];
    __syncthreads();
    if (threadIdx.x < NM) {
        const float* r = &ann[threadIdx.x * 5];
        barea[threadIdx.x] = (r[2] - r[0]) * (r[3] - r[1]);
    }
    __syncthreads();

    float reg_local = 0.0f;
    float pos_local = 0.0f;
    float cls_local = 0.0f;   // correction vs pure negl stream

    if (a < NA) {
        const float4 av = ((const float4*)anchors)[a];
        const float aw = av.z - av.x;
        const float ah = av.w - av.y;
        const float aarea = aw * ah;

        // division-free running argmax: track (best_inter, best_ua), all ua > 0.
        float bi = -1.0f, bu = 1.0f;   // represents iou = -1 (masked)
        int bm = 0;
        #pragma unroll
        for (int m = 0; m < NM; ++m) {
            const float bx1 = ann[m * 5 + 0];
            const float by1 = ann[m * 5 + 1];
            const float bx2 = ann[m * 5 + 2];
            const float by2 = ann[m * 5 + 3];
            const float lbl = ann[m * 5 + 4];
            const float iw = fmaxf(fminf(av.z, bx2) - fmaxf(av.x, bx1), 0.0f);
            const float ih = fmaxf(fminf(av.w, by2) - fmaxf(av.y, by1), 0.0f);
            float inter = iw * ih;
            float ua = fmaxf(aarea + barea[m] - inter, 1e-8f);
            if (lbl == -1.0f) { inter = -1.0f; ua = 1.0f; }   // padding mask -> iou = -1
            // iou_m > best  <=>  inter * bu > bi * ua   (strict > keeps first occurrence)
            if (m == 0 || inter * bu > bi * ua) { bi = inter; bu = ua; bm = m; }
        }

        if (bi >= 0.5f * bu) {
            // POSITIVE anchor
            const int st = (int)ann[bm * 5 + 4];
            const float bx1 = ann[bm * 5 + 0];
            const float by1 = ann[bm * 5 + 1];
            const float bx2 = ann[bm * 5 + 2];
            const float by2 = ann[bm * 5 + 3];
            const float gw0 = bx2 - bx1;
            const float gh0 = by2 - by1;
            const float gcx = bx1 + 0.5f * gw0;
            const float gcy = by1 + 0.5f * gh0;
            const float gw = fmaxf(gw0, 1.0f);
            const float gh = fmaxf(gh0, 1.0f);
            const float acx = av.x + 0.5f * aw;
            const float acy = av.y + 0.5f * ah;
            float rt0 = ((gcx - acx) / aw) / 0.1f;
            float rt1 = ((gcy - acy) / ah) / 0.1f;
            float rt2 = logf(gw / aw) / 0.2f;
            float rt3 = logf(gh / ah) / 0.2f;
            const float4 rg = ((const float4*)regressions)[b * NA + a];
            float s = 0.0f;
            float d;
            d = fabsf(rt0 - rg.x); s += (d <= 1.0f / 9.0f) ? 4.5f * d * d : d - 0.5f / 9.0f;
            d = fabsf(rt1 - rg.y); s += (d <= 1.0f / 9.0f) ? 4.5f * d * d : d - 0.5f / 9.0f;
            d = fabsf(rt2 - rg.z); s += (d <= 1.0f / 9.0f) ? 4.5f * d * d : d - 0.5f / 9.0f;
            d = fabsf(rt3 - rg.w); s += (d <= 1.0f / 9.0f) ? 4.5f * d * d : d - 0.5f / 9.0f;
            reg_local = s;
            pos_local = 1.0f;
            // classification correction at the assigned class: negl -> posl
            const float c = clampc(cls[((size_t)b * NA + a) * NK + st]);
            cls_local = posl(c) - negl(c);
        } else if (bi >= 0.4f * bu) {
            // IGNORE anchor: subtract this whole row's negl contribution
            const float4* row = (const float4*)(cls + ((size_t)b * NA + a) * NK);
            float s = 0.0f;
            #pragma unroll
            for (int f = 0; f < NK / 4; ++f) s += negl4(row[f]);
            cls_local = -s;
        }
        // else NEGATIVE: pure stream already counted it correctly
    }

    // block reduction of (cls_local, reg_local, pos_local) -> plain store
    #pragma unroll
    for (int o = 32; o > 0; o >>= 1) {
        cls_local += __shfl_down(cls_local, o, 64);
        reg_local += __shfl_down(reg_local, o, 64);
        pos_local += __shfl_down(pos_local, o, 64);
    }
    __shared__ float wc[BLK_A / 64], wr[BLK_A / 64], wp[BLK_A / 64];
    const int lane = threadIdx.x & 63;
    const int wid = threadIdx.x >> 6;
    if (lane == 0) { wc[wid] = cls_local; wr[wid] = reg_local; wp[wid] = pos_local; }
    __syncthreads();
    if (threadIdx.x == 0) {
        float csum = 0.0f, rsum = 0.0f, psum = 0.0f;
        #pragma unroll
        for (int i = 0; i < BLK_A / 64; ++i) { csum += wc[i]; rsum += wr[i]; psum += wp[i]; }
        float* q = &a_part[(size_t)blockIdx.x * 3];
        q[0] = csum; q[1] = rsum; q[2] = psum;
    }
}

// Pure-stream focal loss: sum negl over EVERY element (corrections in assign).
__global__ __launch_bounds__(256) void focal_main(
    const float* __restrict__ cls,          // [NB,NA,NK]
    float* __restrict__ f_part)             // [NB*FB_BPB] plain stores
{
    const int b = blockIdx.x / FB_BPB;
    const int blk = blockIdx.x % FB_BPB;
    const float4* __restrict__ p = (const float4*)(cls + (size_t)b * NA * NK);
    const int t = blk * 256 + threadIdx.x;

    float sum = 0.0f;
    #pragma unroll
    for (int o = 0; o < FB_O; ++o) {
        float4 v[FB_U];
        #pragma unroll
        for (int u = 0; u < FB_U; ++u)
            v[u] = p[t + (o * FB_U + u) * FB_STRIDE];
        #pragma unroll
        for (int u = 0; u < FB_U; ++u)
            sum += negl4(v[u]);
    }

    #pragma unroll
    for (int o = 32; o > 0; o >>= 1) sum += __shfl_down(sum, o, 64);
    __shared__ float ws[256 / 64];
    const int lane = threadIdx.x & 63;
    const int wid = threadIdx.x >> 6;
    if (lane == 0) ws[wid] = sum;
    __syncthreads();
    if (threadIdx.x == 0) {
        float s = 0.0f;
        #pragma unroll
        for (int i = 0; i < 4; ++i) s += ws[i];
        f_part[blockIdx.x] = s;
    }
}

// Single-block final reduction: ~16K floats, no atomics anywhere.
__global__ __launch_bounds__(256) void finalize_kernel(
    const float* __restrict__ f_part,
    const float* __restrict__ a_part,
    float* __restrict__ out)
{
    __shared__ float red[3][4];
    float cs_total = 0.0f, rs_total = 0.0f;
    for (int b = 0; b < NB; ++b) {
        float c = 0.0f, r = 0.0f, p = 0.0f;
        for (int i = threadIdx.x; i < FB_BPB; i += 256)
            c += f_part[b * FB_BPB + i];
        for (int i = threadIdx.x; i < BPB_A; i += 256) {
            const float* q = &a_part[(size_t)(b * BPB_A + i) * 3];
            c += q[0]; r += q[1]; p += q[2];
        }
        #pragma unroll
        for (int o = 32; o > 0; o >>= 1) {
            c += __shfl_down(c, o, 64);
            r += __shfl_down(r, o, 64);
            p += __shfl_down(p, o, 64);
        }
        const int lane = threadIdx.x & 63;
        const int wid = threadIdx.x >> 6;
        if (lane == 0) { red[0][wid] = c; red[1][wid] = r; red[2][wid] = p; }
        __syncthreads();
        if (threadIdx.x == 0) {
            const float C = red[0][0] + red[0][1] + red[0][2] + red[0][3];
            const float R = red[1][0] + red[1][1] + red[1][2] + red[1][3];
            const float P = red[2][0] + red[2][1] + red[2][2] + red[2][3];
            cs_total += C / fmaxf(P, 1.0f);
            rs_total += (P > 0.0f) ? R / fmaxf(P * 4.0f, 1.0f) : 0.0f;
        }
        __syncthreads();
    }
    if (threadIdx.x == 0) {
        out[0] = cs_total / (float)NB;
        out[1] = rs_total / (float)NB;
    }
}

extern "C" void kernel_launch(void* const* d_in, const int* in_sizes, int n_in,
                              void* d_out, int out_size, void* d_ws, size_t ws_size,
                              hipStream_t stream) {
    const float* cls = (const float*)d_in[0];   // [NB,NA,NK]
    const float* reg = (const float*)d_in[1];   // [NB,NA,4]
    const float* anc = (const float*)d_in[2];   // [1,NA,4]
    const float* ann = (const float*)d_in[3];   // [NB,NM,5]

    float* f_part = (float*)d_ws;
    float* a_part = (float*)((char*)d_ws + A_PART_OFF);
    float* out = (float*)d_out;

    focal_main<<<NB * FB_BPB, 256, 0, stream>>>(cls, f_part);
    assign_kernel<<<NB * BPB_A, BLK_A, 0, stream>>>(anc, reg, ann, cls, a_part);
    finalize_kernel<<<1, 256, 0, stream>>>(f_part, a_part, out);
}

// Round 5
// 83.927 us; speedup vs baseline: 3.7324x; 1.4564x over previous
//
#include <hip/hip_runtime.h>

#define NB 8
#define NA 120000
#define NK 80
#define NM 32

#define ALPHA_F 0.25f
#define EPS_F 1e-4f

#define BLK 256
#define BPB ((NA + BLK - 1) / BLK)          // 469 blocks per batch item (last has 192 rows)

// ws: float part[NB*BPB][3] (cls, reg, pos) — plain stores, every slot written each launch
__device__ __forceinline__ float clampc(float x) {
    return fminf(fmaxf(x, EPS_F), 1.0f - EPS_F);
}
__device__ __forceinline__ float negl(float c) {
    // t == 0: (1-alpha) * c^2 * (-log(1-c))
    return (1.0f - ALPHA_F) * c * c * (-__logf(1.0f - c));
}
__device__ __forceinline__ float posl(float c) {
    // t == 1: alpha * (1-c)^2 * (-log(c))
    const float omc = 1.0f - c;
    return ALPHA_F * omc * omc * (-__logf(c));
}
__device__ __forceinline__ float negl4(float4 v) {
    return negl(clampc(v.x)) + negl(clampc(v.y)) + negl(clampc(v.z)) + negl(clampc(v.w));
}

__global__ __launch_bounds__(BLK) void fused_kernel(
    const float* __restrict__ anchors,      // [NA,4]
    const float* __restrict__ regressions,  // [NB,NA,4]
    const float* __restrict__ annotations,  // [NB,NM,5]
    const float* __restrict__ cls,          // [NB,NA,NK]
    float* __restrict__ part)               // [NB*BPB,3]
{
    const int b = blockIdx.x / BPB;
    const int blk = blockIdx.x % BPB;
    const int a0 = blk * BLK;
    const int a = a0 + threadIdx.x;

    __shared__ float ann[NM * 5];
    __shared__ float barea[NM];
    __shared__ int s_st[BLK];               // per-row status: class id, -1 ignore, -2 negative
    if (threadIdx.x < NM * 5) ann[threadIdx.x] = annotations[b * NM * 5 + threadIdx.x];
    __syncthreads();
    if (threadIdx.x < NM) {
        const float* r = &ann[threadIdx.x * 5];
        barea[threadIdx.x] = (r[2] - r[0]) * (r[3] - r[1]);
    }
    __syncthreads();

    float reg_local = 0.0f;
    float pos_local = 0.0f;
    float cls_local = 0.0f;

    // ---- phase 1: anchor assignment (one anchor per thread) ----
    int st = -2;
    if (a < NA) {
        const float4 av = ((const float4*)anchors)[a];
        const float aw = av.z - av.x;
        const float ah = av.w - av.y;
        const float aarea = aw * ah;

        // division-free argmax over (inter, ua); strict > keeps first occurrence
        float bi = -1.0f, bu = 1.0f;
        int bm = 0;
        #pragma unroll
        for (int m = 0; m < NM; ++m) {
            const float bx1 = ann[m * 5 + 0];
            const float by1 = ann[m * 5 + 1];
            const float bx2 = ann[m * 5 + 2];
            const float by2 = ann[m * 5 + 3];
            const float lbl = ann[m * 5 + 4];
            const float iw = fmaxf(fminf(av.z, bx2) - fmaxf(av.x, bx1), 0.0f);
            const float ih = fmaxf(fminf(av.w, by2) - fmaxf(av.y, by1), 0.0f);
            float inter = iw * ih;
            float ua = fmaxf(aarea + barea[m] - inter, 1e-8f);
            if (lbl == -1.0f) { inter = -1.0f; ua = 1.0f; }
            if (m == 0 || inter * bu > bi * ua) { bi = inter; bu = ua; bm = m; }
        }

        if (bi >= 0.5f * bu) {
            st = (int)ann[bm * 5 + 4];
            const float bx1 = ann[bm * 5 + 0];
            const float by1 = ann[bm * 5 + 1];
            const float bx2 = ann[bm * 5 + 2];
            const float by2 = ann[bm * 5 + 3];
            const float gw0 = bx2 - bx1;
            const float gh0 = by2 - by1;
            const float gcx = bx1 + 0.5f * gw0;
            const float gcy = by1 + 0.5f * gh0;
            const float gw = fmaxf(gw0, 1.0f);
            const float gh = fmaxf(gh0, 1.0f);
            const float acx = av.x + 0.5f * aw;
            const float acy = av.y + 0.5f * ah;
            const float rt0 = ((gcx - acx) / aw) / 0.1f;
            const float rt1 = ((gcy - acy) / ah) / 0.1f;
            const float rt2 = logf(gw / aw) / 0.2f;
            const float rt3 = logf(gh / ah) / 0.2f;
            const float4 rg = ((const float4*)regressions)[b * NA + a];  // rare, exec-masked
            float s = 0.0f, d;
            d = fabsf(rt0 - rg.x); s += (d <= 1.0f / 9.0f) ? 4.5f * d * d : d - 0.5f / 9.0f;
            d = fabsf(rt1 - rg.y); s += (d <= 1.0f / 9.0f) ? 4.5f * d * d : d - 0.5f / 9.0f;
            d = fabsf(rt2 - rg.z); s += (d <= 1.0f / 9.0f) ? 4.5f * d * d : d - 0.5f / 9.0f;
            d = fabsf(rt3 - rg.w); s += (d <= 1.0f / 9.0f) ? 4.5f * d * d : d - 0.5f / 9.0f;
            reg_local = s;
            pos_local = 1.0f;
        } else if (bi >= 0.4f * bu) {
            st = -1;                         // ignore: row contributes nothing
        }
    }
    s_st[threadIdx.x] = st;
    __syncthreads();

    // ---- phase 2: coalesced stream of this block's cls tile ----
    const float4* __restrict__ p = (const float4*)(cls + ((size_t)b * NA + a0) * NK);
    const int n_rows = (a0 + BLK <= NA) ? BLK : (NA - a0);

    if (n_rows == BLK) {
        // exact 5120 float4: 4 outer x 5-deep batched
        #pragma unroll
        for (int o = 0; o < 4; ++o) {
            float4 v[5];
            #pragma unroll
            for (int u = 0; u < 5; ++u)
                v[u] = p[(o * 5 + u) * BLK + threadIdx.x];
            #pragma unroll
            for (int u = 0; u < 5; ++u) {
                const int idx = (o * 5 + u) * BLK + threadIdx.x;
                const int row = idx / 20;           // const-div -> magic mul
                const int k0 = (idx - row * 20) * 4;
                const int s = s_st[row];
                const float m = (s == -1) ? 0.0f : 1.0f;
                float l = m * negl4(v[u]);
                if (s >= k0 && s < k0 + 4) {        // positive class in window (rare)
                    const float c = clampc((s == k0) ? v[u].x : (s == k0 + 1) ? v[u].y
                                         : (s == k0 + 2) ? v[u].z : v[u].w);
                    l += posl(c) - negl(c);
                }
                cls_local += l;
            }
        }
    } else {
        const int n4 = n_rows * 20;
        for (int idx = threadIdx.x; idx < n4; idx += BLK) {
            const float4 v = p[idx];
            const int row = idx / 20;
            const int k0 = (idx - row * 20) * 4;
            const int s = s_st[row];
            const float m = (s == -1) ? 0.0f : 1.0f;
            float l = m * negl4(v);
            if (s >= k0 && s < k0 + 4) {
                const float c = clampc((s == k0) ? v.x : (s == k0 + 1) ? v.y
                                     : (s == k0 + 2) ? v.z : v.w);
                l += posl(c) - negl(c);
            }
            cls_local += l;
        }
    }

    // ---- block reduction, plain store ----
    #pragma unroll
    for (int o = 32; o > 0; o >>= 1) {
        cls_local += __shfl_down(cls_local, o, 64);
        reg_local += __shfl_down(reg_local, o, 64);
        pos_local += __shfl_down(pos_local, o, 64);
    }
    __shared__ float wc[BLK / 64], wr[BLK / 64], wp[BLK / 64];
    const int lane = threadIdx.x & 63;
    const int wid = threadIdx.x >> 6;
    if (lane == 0) { wc[wid] = cls_local; wr[wid] = reg_local; wp[wid] = pos_local; }
    __syncthreads();
    if (threadIdx.x == 0) {
        float csum = 0.0f, rsum = 0.0f, psum = 0.0f;
        #pragma unroll
        for (int i = 0; i < BLK / 64; ++i) { csum += wc[i]; rsum += wr[i]; psum += wp[i]; }
        float* q = &part[(size_t)blockIdx.x * 3];
        q[0] = csum; q[1] = rsum; q[2] = psum;
    }
}

__global__ __launch_bounds__(256) void finalize_kernel(
    const float* __restrict__ part,
    float* __restrict__ out)
{
    __shared__ float red[3][4];
    float cs_total = 0.0f, rs_total = 0.0f;
    for (int b = 0; b < NB; ++b) {
        float c = 0.0f, r = 0.0f, p = 0.0f;
        for (int i = threadIdx.x; i < BPB; i += 256) {
            const float* q = &part[(size_t)(b * BPB + i) * 3];
            c += q[0]; r += q[1]; p += q[2];
        }
        #pragma unroll
        for (int o = 32; o > 0; o >>= 1) {
            c += __shfl_down(c, o, 64);
            r += __shfl_down(r, o, 64);
            p += __shfl_down(p, o, 64);
        }
        const int lane = threadIdx.x & 63;
        const int wid = threadIdx.x >> 6;
        if (lane == 0) { red[0][wid] = c; red[1][wid] = r; red[2][wid] = p; }
        __syncthreads();
        if (threadIdx.x == 0) {
            const float C = red[0][0] + red[0][1] + red[0][2] + red[0][3];
            const float R = red[1][0] + red[1][1] + red[1][2] + red[1][3];
            const float P = red[2][0] + red[2][1] + red[2][2] + red[2][3];
            cs_total += C / fmaxf(P, 1.0f);
            rs_total += (P > 0.0f) ? R / fmaxf(P * 4.0f, 1.0f) : 0.0f;
        }
        __syncthreads();
    }
    if (threadIdx.x == 0) {
        out[0] = cs_total / (float)NB;
        out[1] = rs_total / (float)NB;
    }
}

extern "C" void kernel_launch(void* const* d_in, const int* in_sizes, int n_in,
                              void* d_out, int out_size, void* d_ws, size_t ws_size,
                              hipStream_t stream) {
    const float* cls = (const float*)d_in[0];   // [NB,NA,NK]
    const float* reg = (const float*)d_in[1];   // [NB,NA,4]
    const float* anc = (const float*)d_in[2];   // [1,NA,4]
    const float* ann = (const float*)d_in[3];   // [NB,NM,5]

    float* part = (float*)d_ws;
    float* out = (float*)d_out;

    fused_kernel<<<NB * BPB, BLK, 0, stream>>>(anc, reg, ann, cls, part);
    finalize_kernel<<<1, 256, 0, stream>>>(part, out);
}

// Round 6
// 83.539 us; speedup vs baseline: 3.7498x; 1.0047x over previous
//
#include <hip/hip_runtime.h>

#define NB 8
#define NA 120000
#define NK 80
#define NM 32

#define ALPHA_F 0.25f
#define EPS_F 1e-4f

#define BLK 256
#define BPB ((NA + BLK - 1) / BLK)          // 469 blocks per batch item (last has 192 rows)

// ws: float part[NB*BPB][4] (cls, reg, pos, pad) — plain stores, every slot written each launch
__device__ __forceinline__ float clampc(float x) {
    return fminf(fmaxf(x, EPS_F), 1.0f - EPS_F);
}
__device__ __forceinline__ float negl(float c) {
    // t == 0: (1-alpha) * c^2 * (-log(1-c))
    return (1.0f - ALPHA_F) * c * c * (-__logf(1.0f - c));
}
__device__ __forceinline__ float posl(float c) {
    // t == 1: alpha * (1-c)^2 * (-log(c))
    const float omc = 1.0f - c;
    return ALPHA_F * omc * omc * (-__logf(c));
}
__device__ __forceinline__ float negl4(float4 v) {
    return negl(clampc(v.x)) + negl(clampc(v.y)) + negl(clampc(v.z)) + negl(clampc(v.w));
}

__global__ __launch_bounds__(BLK) void fused_kernel(
    const float* __restrict__ anchors,      // [NA,4]
    const float* __restrict__ regressions,  // [NB,NA,4]
    const float* __restrict__ annotations,  // [NB,NM,5]
    const float* __restrict__ cls,          // [NB,NA,NK]
    float* __restrict__ part)               // [NB*BPB,4]
{
    const int b = blockIdx.x / BPB;
    const int blk = blockIdx.x % BPB;
    const int a0 = blk * BLK;
    const int a = a0 + threadIdx.x;

    __shared__ float ann[NM * 5];
    __shared__ float barea[NM];
    __shared__ int s_ign[BLK];              // block-local ignore-row list
    __shared__ int s_nign;
    if (threadIdx.x == 0) s_nign = 0;
    if (threadIdx.x < NM * 5) ann[threadIdx.x] = annotations[b * NM * 5 + threadIdx.x];
    __syncthreads();
    if (threadIdx.x < NM) {
        const float* r = &ann[threadIdx.x * 5];
        barea[threadIdx.x] = (r[2] - r[0]) * (r[3] - r[1]);
    }
    __syncthreads();

    float reg_local = 0.0f;
    float pos_local = 0.0f;
    float cls_local = 0.0f;

    // ---- phase 1: anchor assignment (one anchor per thread) ----
    if (a < NA) {
        const float4 av = ((const float4*)anchors)[a];
        const float aw = av.z - av.x;
        const float ah = av.w - av.y;
        const float aarea = aw * ah;

        // division-free argmax over (inter, ua); strict > keeps first occurrence
        float bi = -1.0f, bu = 1.0f;
        int bm = 0;
        #pragma unroll
        for (int m = 0; m < NM; ++m) {
            const float bx1 = ann[m * 5 + 0];
            const float by1 = ann[m * 5 + 1];
            const float bx2 = ann[m * 5 + 2];
            const float by2 = ann[m * 5 + 3];
            const float lbl = ann[m * 5 + 4];
            const float iw = fmaxf(fminf(av.z, bx2) - fmaxf(av.x, bx1), 0.0f);
            const float ih = fmaxf(fminf(av.w, by2) - fmaxf(av.y, by1), 0.0f);
            float inter = iw * ih;
            float ua = fmaxf(aarea + barea[m] - inter, 1e-8f);
            if (lbl == -1.0f) { inter = -1.0f; ua = 1.0f; }
            if (m == 0 || inter * bu > bi * ua) { bi = inter; bu = ua; bm = m; }
        }

        if (bi >= 0.5f * bu) {
            // POSITIVE: smooth-L1 + single-element class correction (rare, exec-masked)
            const int st = (int)ann[bm * 5 + 4];
            const float bx1 = ann[bm * 5 + 0];
            const float by1 = ann[bm * 5 + 1];
            const float bx2 = ann[bm * 5 + 2];
            const float by2 = ann[bm * 5 + 3];
            const float gw0 = bx2 - bx1;
            const float gh0 = by2 - by1;
            const float gcx = bx1 + 0.5f * gw0;
            const float gcy = by1 + 0.5f * gh0;
            const float gw = fmaxf(gw0, 1.0f);
            const float gh = fmaxf(gh0, 1.0f);
            const float acx = av.x + 0.5f * aw;
            const float acy = av.y + 0.5f * ah;
            const float rt0 = ((gcx - acx) / aw) / 0.1f;
            const float rt1 = ((gcy - acy) / ah) / 0.1f;
            const float rt2 = logf(gw / aw) / 0.2f;
            const float rt3 = logf(gh / ah) / 0.2f;
            const float4 rg = ((const float4*)regressions)[b * NA + a];
            float s = 0.0f, d;
            d = fabsf(rt0 - rg.x); s += (d <= 1.0f / 9.0f) ? 4.5f * d * d : d - 0.5f / 9.0f;
            d = fabsf(rt1 - rg.y); s += (d <= 1.0f / 9.0f) ? 4.5f * d * d : d - 0.5f / 9.0f;
            d = fabsf(rt2 - rg.z); s += (d <= 1.0f / 9.0f) ? 4.5f * d * d : d - 0.5f / 9.0f;
            d = fabsf(rt3 - rg.w); s += (d <= 1.0f / 9.0f) ? 4.5f * d * d : d - 0.5f / 9.0f;
            reg_local = s;
            pos_local = 1.0f;
            const float c = clampc(cls[((size_t)b * NA + a) * NK + st]);
            cls_local = posl(c) - negl(c);
        } else if (bi >= 0.4f * bu) {
            // IGNORE: record row for phase-3 subtraction (LDS atomic, few per block)
            const int k = atomicAdd(&s_nign, 1);
            s_ign[k] = threadIdx.x;
        }
        // else NEGATIVE: pure stream counts it correctly
    }
    __syncthreads();

    // ---- phase 2: pure unconditional stream of this block's cls tile ----
    const float4* __restrict__ p = (const float4*)(cls + ((size_t)b * NA + a0) * NK);
    const int n_rows = (a0 + BLK <= NA) ? BLK : (NA - a0);

    if (n_rows == BLK) {
        // exact 5120 float4: 4 outer x 5-deep batched; no index math, no LDS, no branches
        #pragma unroll
        for (int o = 0; o < 4; ++o) {
            float4 v[5];
            #pragma unroll
            for (int u = 0; u < 5; ++u)
                v[u] = p[(o * 5 + u) * BLK + threadIdx.x];
            #pragma unroll
            for (int u = 0; u < 5; ++u)
                cls_local += negl4(v[u]);
        }
    } else {
        const int n4 = n_rows * 20;
        for (int idx = threadIdx.x; idx < n4; idx += BLK)
            cls_local += negl4(p[idx]);
    }

    // ---- phase 3: subtract ignore rows (L1/L2-resident re-read) ----
    const int nign = s_nign;
    if (nign > 0) {
        const int total = nign * 20;
        for (int i = threadIdx.x; i < total; i += BLK) {
            const int e = i / 20;
            const int f = i - e * 20;
            const int r = s_ign[e];
            cls_local -= negl4(p[r * 20 + f]);
        }
    }

    // ---- block reduction, plain store ----
    #pragma unroll
    for (int o = 32; o > 0; o >>= 1) {
        cls_local += __shfl_down(cls_local, o, 64);
        reg_local += __shfl_down(reg_local, o, 64);
        pos_local += __shfl_down(pos_local, o, 64);
    }
    __shared__ float wc[BLK / 64], wr[BLK / 64], wp[BLK / 64];
    const int lane = threadIdx.x & 63;
    const int wid = threadIdx.x >> 6;
    if (lane == 0) { wc[wid] = cls_local; wr[wid] = reg_local; wp[wid] = pos_local; }
    __syncthreads();
    if (threadIdx.x == 0) {
        float csum = 0.0f, rsum = 0.0f, psum = 0.0f;
        #pragma unroll
        for (int i = 0; i < BLK / 64; ++i) { csum += wc[i]; rsum += wr[i]; psum += wp[i]; }
        float4 q;
        q.x = csum; q.y = rsum; q.z = psum; q.w = 0.0f;
        ((float4*)part)[blockIdx.x] = q;
    }
}

__global__ __launch_bounds__(256) void finalize_kernel(
    const float* __restrict__ part,
    float* __restrict__ out)
{
    __shared__ float red[3][4];
    float cs_total = 0.0f, rs_total = 0.0f;
    for (int b = 0; b < NB; ++b) {
        float c = 0.0f, r = 0.0f, p = 0.0f;
        for (int i = threadIdx.x; i < BPB; i += 256) {
            const float4 q = ((const float4*)part)[b * BPB + i];
            c += q.x; r += q.y; p += q.z;
        }
        #pragma unroll
        for (int o = 32; o > 0; o >>= 1) {
            c += __shfl_down(c, o, 64);
            r += __shfl_down(r, o, 64);
            p += __shfl_down(p, o, 64);
        }
        const int lane = threadIdx.x & 63;
        const int wid = threadIdx.x >> 6;
        if (lane == 0) { red[0][wid] = c; red[1][wid] = r; red[2][wid] = p; }
        __syncthreads();
        if (threadIdx.x == 0) {
            const float C = red[0][0] + red[0][1] + red[0][2] + red[0][3];
            const float R = red[1][0] + red[1][1] + red[1][2] + red[1][3];
            const float P = red[2][0] + red[2][1] + red[2][2] + red[2][3];
            cs_total += C / fmaxf(P, 1.0f);
            rs_total += (P > 0.0f) ? R / fmaxf(P * 4.0f, 1.0f) : 0.0f;
        }
        __syncthreads();
    }
    if (threadIdx.x == 0) {
        out[0] = cs_total / (float)NB;
        out[1] = rs_total / (float)NB;
    }
}

extern "C" void kernel_launch(void* const* d_in, const int* in_sizes, int n_in,
                              void* d_out, int out_size, void* d_ws, size_t ws_size,
                              hipStream_t stream) {
    const float* cls = (const float*)d_in[0];   // [NB,NA,NK]
    const float* reg = (const float*)d_in[1];   // [NB,NA,4]
    const float* anc = (const float*)d_in[2];   // [1,NA,4]
    const float* ann = (const float*)d_in[3];   // [NB,NM,5]

    float* part = (float*)d_ws;
    float* out = (float*)d_out;

    fused_kernel<<<NB * BPB, BLK, 0, stream>>>(anc, reg, ann, cls, part);
    finalize_kernel<<<1, 256, 0, stream>>>(part, out);
}